// Round 1
// baseline (191.262 us; speedup 1.0000x reference)
//
#include <hip/hip_runtime.h>

#define FRAME 160
#define ORDER 16
#define LPC_EPS 1e-8f
#define AW 20  // padded coeff stride (floats) for float4-aligned ws accesses

// ---------------------------------------------------------------------------
// K1: one thread per frame. Autocorrelation (lags 0..16) + Levinson-Durbin.
// Chunked register window (5 chunks x 48 floats, zero-padded past frame end)
// keeps every index compile-time -> pure-register, no scratch.
// ---------------------------------------------------------------------------
__global__ __launch_bounds__(256) void lpc_analyze(const float* __restrict__ x,
                                                   float* __restrict__ aws,
                                                   int n_frames) {
    int f = blockIdx.x * 256 + threadIdx.x;
    if (f >= n_frames) return;
    const float* frm = x + (long long)f * FRAME;

    float r[ORDER + 1];
#pragma unroll
    for (int k = 0; k <= ORDER; ++k) r[k] = 0.f;

    // r[k] = sum_{n=0}^{159} x[n]*x[n+k] with x[>=160] := 0  (exact zero-pad form)
    for (int c = 0; c < 5; ++c) {
        int boff = c * 32;
        float w[48];
#pragma unroll
        for (int m = 0; m < 12; ++m) {
            int idx = boff + 4 * m;  // wave-uniform condition (c,m only)
            float4 v = (idx + 3 < FRAME) ? *(const float4*)(frm + idx)
                                         : make_float4(0.f, 0.f, 0.f, 0.f);
            w[4 * m + 0] = v.x; w[4 * m + 1] = v.y;
            w[4 * m + 2] = v.z; w[4 * m + 3] = v.w;
        }
#pragma unroll
        for (int n = 0; n < 32; ++n) {
#pragma unroll
            for (int k = 0; k <= ORDER; ++k) {
                r[k] = fmaf(w[n], w[n + k], r[k]);
            }
        }
    }

    // Levinson-Durbin, fully unrolled (ORDER=16), all in registers.
    float a[ORDER + 1];
    a[0] = 1.f;
#pragma unroll
    for (int j = 1; j <= ORDER; ++j) a[j] = 0.f;
    float e = (r[0] != 0.f) ? r[0] : LPC_EPS;  // e >= EPS > 0 from here on
#pragma unroll
    for (int i = 1; i <= ORDER; ++i) {
        float acc = r[i];
#pragma unroll
        for (int j = 1; j < i; ++j) acc -= a[j] * r[i - j];
        float k = acc / e;  // e != 0 guaranteed (>= EPS), matches ref's safe_e path
        float na[ORDER + 1];
#pragma unroll
        for (int j = 1; j < i; ++j) na[j] = a[j] - k * a[i - j];
#pragma unroll
        for (int j = 1; j < i; ++j) a[j] = na[j];
        a[i] = k;
        e = fmaxf(e * (1.f - k * k), LPC_EPS);
    }

    // Store coeffs, padded to 20 floats for aligned float4 writes/reads.
    float o20[AW];
#pragma unroll
    for (int k = 0; k <= ORDER; ++k) o20[k] = a[k];
#pragma unroll
    for (int k = ORDER + 1; k < AW; ++k) o20[k] = 0.f;
    float* ap = aws + (long long)f * AW;
#pragma unroll
    for (int m = 0; m < AW / 4; ++m) {
        *(float4*)(ap + 4 * m) =
            make_float4(o20[4 * m], o20[4 * m + 1], o20[4 * m + 2], o20[4 * m + 3]);
    }
}

// ---------------------------------------------------------------------------
// K2: FIR inverse filter. One thread per 4 consecutive samples (quad-aligned,
// frame-local zero padding is per-float4 since n0 % 4 == 0).
// res[n] = sum_{k=0}^{16} a[k] * x[n-k]
// ---------------------------------------------------------------------------
__global__ __launch_bounds__(256) void lpc_fir(const float* __restrict__ x,
                                               const float* __restrict__ aws,
                                               float* __restrict__ out,
                                               int n_quads) {
    int q = blockIdx.x * 256 + threadIdx.x;
    if (q >= n_quads) return;
    int f = q / (FRAME / 4);           // 40 quads per frame
    int n0 = (q - f * (FRAME / 4)) * 4;
    const float* frm = x + (long long)f * FRAME;

    // coefficients (shared by 40 consecutive threads -> L1 broadcast)
    const float* ap = aws + (long long)f * AW;
    float a[ORDER + 1];
#pragma unroll
    for (int m = 0; m < 4; ++m) {
        float4 v = *(const float4*)(ap + 4 * m);
        a[4 * m + 0] = v.x; a[4 * m + 1] = v.y;
        a[4 * m + 2] = v.z; a[4 * m + 3] = v.w;
    }
    a[16] = ap[16];

    // window w[0..19] = frm[n0-16 .. n0+3], zeros before frame start
    float w[20];
#pragma unroll
    for (int m = 0; m < 5; ++m) {
        int idx = n0 - 16 + 4 * m;
        float4 v = (idx >= 0) ? *(const float4*)(frm + idx)
                              : make_float4(0.f, 0.f, 0.f, 0.f);
        w[4 * m + 0] = v.x; w[4 * m + 1] = v.y;
        w[4 * m + 2] = v.z; w[4 * m + 3] = v.w;
    }

    float o[4];
#pragma unroll
    for (int m = 0; m < 4; ++m) {
        float s = 0.f;
#pragma unroll
        for (int k = 0; k <= ORDER; ++k) {
            s = fmaf(a[k], w[16 + m - k], s);
        }
        o[m] = s;
    }
    *(float4*)(out + (long long)f * FRAME + n0) = make_float4(o[0], o[1], o[2], o[3]);
}

extern "C" void kernel_launch(void* const* d_in, const int* in_sizes, int n_in,
                              void* d_out, int out_size, void* d_ws, size_t ws_size,
                              hipStream_t stream) {
    const float* x = (const float*)d_in[0];
    float* out = (float*)d_out;
    int total = in_sizes[0];           // 20,480,000 (multiple of FRAME)
    int n_frames = total / FRAME;      // 128,000
    int n_quads = total / 4;           // 5,120,000
    float* aws = (float*)d_ws;         // 128,000 * 20 * 4 B = 10.24 MB scratch

    lpc_analyze<<<(n_frames + 255) / 256, 256, 0, stream>>>(x, aws, n_frames);
    lpc_fir<<<(n_quads + 255) / 256, 256, 0, stream>>>(x, aws, out, n_quads);
}

// Round 2
// 145.550 us; speedup vs baseline: 1.3141x; 1.3141x over previous
//
#include <hip/hip_runtime.h>

#define FRAME 160
#define ORDER 16
#define LPC_EPS 1e-8f
#define NF 64        // frames per block
#define BS 256       // threads per block (4 waves); 4 threads per frame
#define SX 164       // padded LDS row stride in floats (164*4=656 B, 16B-aligned, +4-bank skew)
#define QPB (NF * FRAME / 4 / BS)  // 10 float4 iterations per thread for stage-in/out

// One block handles 64 frames end-to-end:
//   stage-in (coalesced) -> autocorr (4-way split per frame, shfl reduce)
//   -> Levinson (redundant per quad-lane, coeffs stay in registers)
//   -> FIR in-place into LDS -> stage-out (coalesced).
__global__ __launch_bounds__(BS, 3) void lpc_fused(const float* __restrict__ x,
                                                   float* __restrict__ out) {
    __shared__ float xs[NF * SX];  // 41.98 KB -> 3 blocks/CU

    const int t = threadIdx.x;
    const long long base = (long long)blockIdx.x * (NF * FRAME);

    // ---- stage in: 2560 consecutive float4, fully coalesced ----
#pragma unroll
    for (int it = 0; it < QPB; ++it) {
        int p = it * BS + t;              // quad index within block [0,2560)
        int f = p / 40;                   // 40 quads per frame
        int off = (p - f * 40) * 4;
        float4 v = *(const float4*)(x + base + 4 * p);
        *(float4*)(&xs[f * SX + off]) = v;
    }
    __syncthreads();

    const int fi = t >> 2;    // frame within block
    const int part = t & 3;   // n-range part: n in [40*part, 40*part+40)
    const int sbase = 40 * part;

    // ---- window w[j] = x[sbase + j], j in [0,56), zero-padded past frame end ----
    float w[56];
#pragma unroll
    for (int m = 0; m < 14; ++m) {
        int idx = sbase + 4 * m;
        float4 v = make_float4(0.f, 0.f, 0.f, 0.f);
        if (idx < FRAME) v = *(const float4*)(&xs[fi * SX + idx]);
        w[4 * m + 0] = v.x; w[4 * m + 1] = v.y;
        w[4 * m + 2] = v.z; w[4 * m + 3] = v.w;
    }

    // ---- partial autocorrelation over this part's 40 samples, all 17 lags ----
    float r[ORDER + 1];
#pragma unroll
    for (int k = 0; k <= ORDER; ++k) r[k] = 0.f;
#pragma unroll
    for (int n = 0; n < 40; ++n) {
#pragma unroll
        for (int k = 0; k <= ORDER; ++k) {
            r[k] = fmaf(w[n], w[n + k], r[k]);
        }
    }
    // quad butterfly: every lane of the quad gets the full-frame r[k]
#pragma unroll
    for (int k = 0; k <= ORDER; ++k) {
        r[k] += __shfl_xor(r[k], 1);
        r[k] += __shfl_xor(r[k], 2);
    }

    // ---- Levinson-Durbin (redundant across the 4 quad lanes; result in regs) ----
    float a[ORDER + 1];
    a[0] = 1.f;
#pragma unroll
    for (int j = 1; j <= ORDER; ++j) a[j] = 0.f;
    float e = (r[0] != 0.f) ? r[0] : LPC_EPS;  // e >= EPS > 0 afterwards
#pragma unroll
    for (int i = 1; i <= ORDER; ++i) {
        float acc = r[i];
#pragma unroll
        for (int j = 1; j < i; ++j) acc -= a[j] * r[i - j];
        float k = acc / e;
        float na[ORDER + 1];
#pragma unroll
        for (int j = 1; j < i; ++j) na[j] = a[j] - k * a[i - j];
#pragma unroll
        for (int j = 1; j < i; ++j) a[j] = na[j];
        a[i] = k;
        e = fmaxf(e * (1.f - k * k), LPC_EPS);
    }

    // ---- FIR look-back: pre[j] = x[sbase - 16 + j], zeros before frame start ----
    float pre[16];
#pragma unroll
    for (int m = 0; m < 4; ++m) {
        int idx = sbase - 16 + 4 * m;
        float4 v = make_float4(0.f, 0.f, 0.f, 0.f);
        if (idx >= 0) v = *(const float4*)(&xs[fi * SX + idx]);
        pre[4 * m + 0] = v.x; pre[4 * m + 1] = v.y;
        pre[4 * m + 2] = v.z; pre[4 * m + 3] = v.w;
    }

    __syncthreads();  // ALL xs reads done before in-place overwrite

    // ---- FIR: res[sbase+n] = sum_k a[k] * x[sbase+n-k], written in place ----
#pragma unroll
    for (int m = 0; m < 10; ++m) {
        float o[4];
#pragma unroll
        for (int i = 0; i < 4; ++i) {
            int n = 4 * m + i;
            float s = 0.f;
#pragma unroll
            for (int k = 0; k <= ORDER; ++k) {
                int j = n - k;                       // compile-time
                float xv = (j >= 0) ? w[j] : pre[16 + j];
                s = fmaf(a[k], xv, s);
            }
            o[i] = s;
        }
        *(float4*)(&xs[fi * SX + sbase + 4 * m]) = make_float4(o[0], o[1], o[2], o[3]);
    }
    __syncthreads();

    // ---- stage out: fully coalesced ----
#pragma unroll
    for (int it = 0; it < QPB; ++it) {
        int p = it * BS + t;
        int f = p / 40;
        int off = (p - f * 40) * 4;
        float4 v = *(const float4*)(&xs[f * SX + off]);
        *(float4*)(out + base + 4 * p) = v;
    }
}

extern "C" void kernel_launch(void* const* d_in, const int* in_sizes, int n_in,
                              void* d_out, int out_size, void* d_ws, size_t ws_size,
                              hipStream_t stream) {
    const float* x = (const float*)d_in[0];
    float* out = (float*)d_out;
    int total = in_sizes[0];                 // 20,480,000 = 128,000 frames
    int n_frames = total / FRAME;
    int n_blocks = n_frames / NF;            // 2000 (exact for this problem shape)
    lpc_fused<<<n_blocks, BS, 0, stream>>>(x, out);
}